// Round 2
// baseline (1301.894 us; speedup 1.0000x reference)
//
#include <hip/hip_runtime.h>

// NerfModel: voxel-grid gather + SH-deg2 eval, with counting-sort by voxel
// index to fix DRAM row locality of the 112 B random gather.
//   P0: zero histogram
//   P1: per-point voxel index + bucket histogram (global atomics, L2-resident)
//   P2: single-block exclusive scan of 8192 buckets -> cursor[], count
//   P3: scatter (id, vidx) pairs into sorted order; zero out[] for unmasked
//   P4: gather in sorted order (block = contiguous chunk of sorted points),
//       SH eval, scattered writes to out (out region is L3-resident)

constexpr float kScale = 1.5f;
constexpr int   kN     = 200;
constexpr int   NB     = 8192;   // buckets
constexpr int   BSHIFT = 10;     // bucket = vidx >> 10 (vidx < 8e6 -> 7813 buckets)
constexpr unsigned kInvalid = 0xFFFFFFFFu;

__global__ __launch_bounds__(256) void p0_zero(unsigned* __restrict__ hist) {
    int i = blockIdx.x * blockDim.x + threadIdx.x;
    if (i < NB) hist[i] = 0u;
}

__global__ __launch_bounds__(256) void p1_hist(
    const float* __restrict__ x,
    unsigned* __restrict__ vidx,
    unsigned* __restrict__ hist,
    int M)
{
    int i = blockIdx.x * blockDim.x + threadIdx.x;
    if (i >= M) return;
    const float x0 = x[3 * i + 0];
    const float x1 = x[3 * i + 1];
    const float x2 = x[3 * i + 2];
    const bool mask = (fabsf(x0) < kScale) && (fabsf(x1) < kScale) && (fabsf(x2) < kScale);
    unsigned v = kInvalid;
    if (mask) {
        const float h = 2.0f * kScale / (float)kN;   // 0.015f
        int i0 = (int)(x0 / h + 0.5f * (float)kN);
        int i1 = (int)(x1 / h + 0.5f * (float)kN);
        int i2 = (int)(x2 / h + 0.5f * (float)kN);
        i0 = min(max(i0, 0), kN - 1);
        i1 = min(max(i1, 0), kN - 1);
        i2 = min(max(i2, 0), kN - 1);
        v = (unsigned)((i0 * kN + i1) * kN + i2);
        atomicAdd(&hist[v >> BSHIFT], 1u);
    }
    vidx[i] = v;
}

__global__ __launch_bounds__(1024) void p2_scan(
    const unsigned* __restrict__ hist,
    unsigned* __restrict__ cursor,
    unsigned* __restrict__ count)
{
    __shared__ unsigned s[1024];
    const int tid = threadIdx.x;
    unsigned running = 0;
    for (int c = 0; c < NB; c += 1024) {
        unsigned val = hist[c + tid];
        s[tid] = val;
        __syncthreads();
        for (int off = 1; off < 1024; off <<= 1) {
            unsigned t = (tid >= off) ? s[tid - off] : 0u;
            __syncthreads();
            s[tid] += t;
            __syncthreads();
        }
        unsigned incl = s[tid];
        cursor[c + tid] = running + (incl - val);   // exclusive base
        unsigned tot = s[1023];
        __syncthreads();
        running += tot;
    }
    if (tid == 0) count[0] = running;
}

__global__ __launch_bounds__(256) void p3_scatter(
    const unsigned* __restrict__ vidx,
    unsigned* __restrict__ cursor,
    uint2* __restrict__ sorted,
    float* __restrict__ out,
    int M)
{
    int i = blockIdx.x * blockDim.x + threadIdx.x;
    if (i >= M) return;
    unsigned v = vidx[i];
    if (v == kInvalid) {
        out[3 * i + 0] = 0.0f;
        out[3 * i + 1] = 0.0f;
        out[3 * i + 2] = 0.0f;
        out[(size_t)3 * M + i] = 0.0f;
    } else {
        unsigned pos = atomicAdd(&cursor[v >> BSHIFT], 1u);
        sorted[pos] = make_uint2((unsigned)i, v);
    }
}

__global__ __launch_bounds__(256) void p4_gather(
    const uint2* __restrict__ sorted,
    const unsigned* __restrict__ count,
    const float* __restrict__ grid,
    const float* __restrict__ dir,
    float* __restrict__ out,
    int M)
{
    const unsigned n = count[0];
    const unsigned nb = gridDim.x;
    const unsigned chunk = (n + nb - 1) / nb;
    const unsigned start = blockIdx.x * chunk;
    const unsigned end = min(start + chunk, n);

    for (unsigned j = start + threadIdx.x; j < end; j += blockDim.x) {
        const uint2 e = sorted[j];
        const unsigned id = e.x;
        const unsigned v  = e.y;

        const float4* __restrict__ g4 =
            reinterpret_cast<const float4*>(grid + (size_t)v * 28u);
        const float4 t0 = g4[0];
        const float4 t1 = g4[1];
        const float4 t2 = g4[2];
        const float4 t3 = g4[3];
        const float4 t4 = g4[4];
        const float4 t5 = g4[5];
        const float4 t6 = g4[6];

        const float dx = dir[3 * id + 0];
        const float dy = dir[3 * id + 1];
        const float dz = dir[3 * id + 2];

        const float b0 = 0.282095f;
        const float b1 = -0.488603f * dy;
        const float b2 =  0.488603f * dz;
        const float b3 = -0.488603f * dx;
        const float b4 =  1.092548f * dx * dy;
        const float b5 = -1.092548f * dy * dz;
        const float b6 =  0.315392f * (2.0f * dz * dz - dx * dx - dy * dy);
        const float b7 = -1.092548f * dx * dz;
        const float b8 =  0.546274f * (dx * dx - dy * dy);

        const float c0 = b0 * t0.y + b1 * t0.z + b2 * t0.w + b3 * t1.x + b4 * t1.y
                       + b5 * t1.z + b6 * t1.w + b7 * t2.x + b8 * t2.y;
        const float c1 = b0 * t2.z + b1 * t2.w + b2 * t3.x + b3 * t3.y + b4 * t3.z
                       + b5 * t3.w + b6 * t4.x + b7 * t4.y + b8 * t4.z;
        const float c2 = b0 * t4.w + b1 * t5.x + b2 * t5.y + b3 * t5.z + b4 * t5.w
                       + b5 * t6.x + b6 * t6.y + b7 * t6.z + b8 * t6.w;

        out[3 * id + 0] = c0;
        out[3 * id + 1] = c1;
        out[3 * id + 2] = c2;
        out[(size_t)3 * M + id] = fmaxf(t0.x, 0.0f);
    }
}

extern "C" void kernel_launch(void* const* d_in, const int* in_sizes, int n_in,
                              void* d_out, int out_size, void* d_ws, size_t ws_size,
                              hipStream_t stream) {
    const float* x    = (const float*)d_in[0];
    const float* dir  = (const float*)d_in[1];
    const float* grid = (const float*)d_in[2];
    float* out = (float*)d_out;

    const int M = in_sizes[0] / 3;   // 4194304

    // Workspace layout (all 256 B-aligned): vidx[M] u32, sorted[M] uint2,
    // hist[NB] u32, cursor[NB] u32, count u32.
    char* base = (char*)d_ws;
    size_t o = 0;
    unsigned* vidx   = (unsigned*)(base + o); o += (size_t)M * 4;
    uint2*    sorted = (uint2*)   (base + o); o += (size_t)M * 8;
    unsigned* hist   = (unsigned*)(base + o); o += (size_t)NB * 4;
    unsigned* cursor = (unsigned*)(base + o); o += (size_t)NB * 4;
    unsigned* count  = (unsigned*)(base + o); o += 256;

    const int block = 256;
    const int gM = (M + block - 1) / block;

    p0_zero   <<<(NB + block - 1) / block, block, 0, stream>>>(hist);
    p1_hist   <<<gM, block, 0, stream>>>(x, vidx, hist, M);
    p2_scan   <<<1, 1024, 0, stream>>>(hist, cursor, count);
    p3_scatter<<<gM, block, 0, stream>>>(vidx, cursor, sorted, out, M);
    p4_gather <<<4096, block, 0, stream>>>(sorted, count, grid, dir, out, M);
}

// Round 3
// 1242.263 us; speedup vs baseline: 1.0480x; 1.0480x over previous
//
#include <hip/hip_runtime.h>

// NerfModel: voxel gather + SH-deg2, counting-sorted so EVERY pass is either
// coalesced or locality-friendly:
//   P1 histogram buckets   P2 scan   P3 payload scatter (bucket-local)
//   P4 sorted gather+eval (in-place rec overwrite)   P5 un-permute via gather.

constexpr float kScale = 1.5f;
constexpr int   kN     = 200;
constexpr int   NB     = 8192;   // buckets (vidx >> 10)
constexpr int   BSHIFT = 10;
constexpr unsigned kInvalid = 0xFFFFFFFFu;

__device__ __forceinline__ unsigned voxel_index(float x0, float x1, float x2, bool& mask) {
    mask = (fabsf(x0) < kScale) && (fabsf(x1) < kScale) && (fabsf(x2) < kScale);
    if (!mask) return kInvalid;
    const float h = 2.0f * kScale / (float)kN;   // 0.015f
    int i0 = (int)(x0 / h + 0.5f * (float)kN);
    int i1 = (int)(x1 / h + 0.5f * (float)kN);
    int i2 = (int)(x2 / h + 0.5f * (float)kN);
    i0 = min(max(i0, 0), kN - 1);
    i1 = min(max(i1, 0), kN - 1);
    i2 = min(max(i2, 0), kN - 1);
    return (unsigned)((i0 * kN + i1) * kN + i2);
}

__global__ __launch_bounds__(256) void p0_zero(unsigned* __restrict__ hist) {
    int i = blockIdx.x * blockDim.x + threadIdx.x;
    if (i < NB) hist[i] = 0u;
}

__global__ __launch_bounds__(256) void p1_hist(
    const float* __restrict__ x,
    unsigned* __restrict__ hist,
    int M)
{
    int i = blockIdx.x * blockDim.x + threadIdx.x;
    if (i >= M) return;
    bool mask;
    unsigned v = voxel_index(x[3 * i], x[3 * i + 1], x[3 * i + 2], mask);
    if (mask) atomicAdd(&hist[v >> BSHIFT], 1u);
}

__global__ __launch_bounds__(1024) void p2_scan(
    const unsigned* __restrict__ hist,
    unsigned* __restrict__ cursor,
    unsigned* __restrict__ count)
{
    __shared__ unsigned s[1024];
    const int tid = threadIdx.x;
    unsigned running = 0;
    for (int c = 0; c < NB; c += 1024) {
        unsigned val = hist[c + tid];
        s[tid] = val;
        __syncthreads();
        for (int off = 1; off < 1024; off <<= 1) {
            unsigned t = (tid >= off) ? s[tid - off] : 0u;
            __syncthreads();
            s[tid] += t;
            __syncthreads();
        }
        cursor[c + tid] = running + (s[tid] - val);   // exclusive base
        unsigned tot = s[1023];
        __syncthreads();
        running += tot;
    }
    if (tid == 0) count[0] = running;
}

__global__ __launch_bounds__(256) void p3_scatter(
    const float* __restrict__ x,
    const float* __restrict__ dir,
    unsigned* __restrict__ cursor,
    unsigned* __restrict__ rank,
    float4* __restrict__ rec,
    int M)
{
    int i = blockIdx.x * blockDim.x + threadIdx.x;
    if (i >= M) return;
    bool mask;
    unsigned v = voxel_index(x[3 * i], x[3 * i + 1], x[3 * i + 2], mask);
    if (!mask) {
        rank[i] = kInvalid;
        return;
    }
    unsigned pos = atomicAdd(&cursor[v >> BSHIFT], 1u);
    rank[i] = pos;
    rec[pos] = make_float4(__uint_as_float(v),
                           dir[3 * i], dir[3 * i + 1], dir[3 * i + 2]);
}

__global__ __launch_bounds__(256) void p4_gather(
    float4* __restrict__ rec,
    const unsigned* __restrict__ count,
    const float* __restrict__ grid)
{
    const unsigned n = count[0];
    const unsigned nb = gridDim.x;
    const unsigned chunk = (n + nb - 1) / nb;
    const unsigned start = blockIdx.x * chunk;
    const unsigned end = min(start + chunk, n);

    for (unsigned j = start + threadIdx.x; j < end; j += blockDim.x) {
        const float4 e = rec[j];
        const unsigned v = __float_as_uint(e.x);
        const float dx = e.y, dy = e.z, dz = e.w;

        const float4* __restrict__ g4 =
            reinterpret_cast<const float4*>(grid + (size_t)v * 28u);
        const float4 t0 = g4[0];
        const float4 t1 = g4[1];
        const float4 t2 = g4[2];
        const float4 t3 = g4[3];
        const float4 t4 = g4[4];
        const float4 t5 = g4[5];
        const float4 t6 = g4[6];

        const float b0 = 0.282095f;
        const float b1 = -0.488603f * dy;
        const float b2 =  0.488603f * dz;
        const float b3 = -0.488603f * dx;
        const float b4 =  1.092548f * dx * dy;
        const float b5 = -1.092548f * dy * dz;
        const float b6 =  0.315392f * (2.0f * dz * dz - dx * dx - dy * dy);
        const float b7 = -1.092548f * dx * dz;
        const float b8 =  0.546274f * (dx * dx - dy * dy);

        const float c0 = b0 * t0.y + b1 * t0.z + b2 * t0.w + b3 * t1.x + b4 * t1.y
                       + b5 * t1.z + b6 * t1.w + b7 * t2.x + b8 * t2.y;
        const float c1 = b0 * t2.z + b1 * t2.w + b2 * t3.x + b3 * t3.y + b4 * t3.z
                       + b5 * t3.w + b6 * t4.x + b7 * t4.y + b8 * t4.z;
        const float c2 = b0 * t4.w + b1 * t5.x + b2 * t5.y + b3 * t5.z + b4 * t5.w
                       + b5 * t6.x + b6 * t6.y + b7 * t6.z + b8 * t6.w;

        rec[j] = make_float4(c0, c1, c2, fmaxf(t0.x, 0.0f));  // in-place overwrite
    }
}

__global__ __launch_bounds__(256) void p5_unpermute(
    const unsigned* __restrict__ rank,
    const float4* __restrict__ rec,
    float* __restrict__ out,
    int M)
{
    int i = blockIdx.x * blockDim.x + threadIdx.x;
    if (i >= M) return;
    unsigned r = rank[i];
    float4 res = make_float4(0.0f, 0.0f, 0.0f, 0.0f);
    if (r != kInvalid) res = rec[r];     // 16 B gather from ~28 MB (L3-resident)
    out[3 * i + 0] = res.x;
    out[3 * i + 1] = res.y;
    out[3 * i + 2] = res.z;
    out[(size_t)3 * M + i] = res.w;
}

extern "C" void kernel_launch(void* const* d_in, const int* in_sizes, int n_in,
                              void* d_out, int out_size, void* d_ws, size_t ws_size,
                              hipStream_t stream) {
    const float* x    = (const float*)d_in[0];
    const float* dir  = (const float*)d_in[1];
    const float* grid = (const float*)d_in[2];
    float* out = (float*)d_out;

    const int M = in_sizes[0] / 3;   // 4194304

    // Workspace: rank[M] u32 | rec[M] float4 | hist[NB] | cursor[NB] | count
    char* base = (char*)d_ws;
    size_t o = 0;
    unsigned* rank   = (unsigned*)(base + o); o += (size_t)M * 4;
    float4*   rec    = (float4*)  (base + o); o += (size_t)M * 16;
    unsigned* hist   = (unsigned*)(base + o); o += (size_t)NB * 4;
    unsigned* cursor = (unsigned*)(base + o); o += (size_t)NB * 4;
    unsigned* count  = (unsigned*)(base + o); o += 256;

    const int block = 256;
    const int gM = (M + block - 1) / block;

    p0_zero     <<<(NB + block - 1) / block, block, 0, stream>>>(hist);
    p1_hist     <<<gM, block, 0, stream>>>(x, hist, M);
    p2_scan     <<<1, 1024, 0, stream>>>(hist, cursor, count);
    p3_scatter  <<<gM, block, 0, stream>>>(x, dir, cursor, rank, rec, M);
    p4_gather   <<<4096, block, 0, stream>>>(rec, count, grid);
    p5_unpermute<<<gM, block, 0, stream>>>(rank, rec, out, M);
}

// Round 4
// 1087.218 us; speedup vs baseline: 1.1975x; 1.1426x over previous
//
#include <hip/hip_runtime.h>

// NerfModel: single-pass voxel-grid gather + SH-deg2 eval.
//   inputs : x (M,3) f32, d (M,3) f32, voxel_grid (200,200,200,28) f32
//   outputs: color (M,3) f32 then sigma (M,) f32, concatenated in d_out.
//
// R3 post-mortem: dur_us includes ~900 us of per-iteration harness reset
// (3.5 GB ws poison + 896 MB grid restore) — our kernel is the remaining
// ~130-180 us. Counting-sort (R2/R3) structurally loses: sorted gather saves
// ~30-60 us of HBM but the sort passes cost >=150 us. Single pass, random
// gather, maximum outstanding loads, nontemporal stores.

constexpr float kScale = 1.5f;
constexpr int   kN     = 200;

__global__ __launch_bounds__(256) void nerf_fwd(
    const float* __restrict__ x,
    const float* __restrict__ dir,
    const float* __restrict__ grid,
    float* __restrict__ out,      // [3M color][M sigma]
    int M)
{
    int i = blockIdx.x * blockDim.x + threadIdx.x;
    if (i >= M) return;

    const float x0 = x[3 * i + 0];
    const float x1 = x[3 * i + 1];
    const float x2 = x[3 * i + 2];

    const bool mask = (fabsf(x0) < kScale) && (fabsf(x1) < kScale) && (fabsf(x2) < kScale);

    float c0 = 0.0f, c1 = 0.0f, c2 = 0.0f, sg = 0.0f;

    if (mask) {
        // idx = clip((int)(x / (2*SCALE/N) + N/2), 0, N-1); trunc == astype(int32)
        const float h = 2.0f * kScale / (float)kN;   // 0.015f
        int i0 = (int)(x0 / h + 0.5f * (float)kN);
        int i1 = (int)(x1 / h + 0.5f * (float)kN);
        int i2 = (int)(x2 / h + 0.5f * (float)kN);
        i0 = min(max(i0, 0), kN - 1);
        i1 = min(max(i1, 0), kN - 1);
        i2 = min(max(i2, 0), kN - 1);

        const size_t voff = (size_t)((i0 * kN + i1) * kN + i2) * 28u;
        const float4* __restrict__ g4 = reinterpret_cast<const float4*>(grid + voff);

        // Issue all 10 loads (7 grid float4 + 3 dir floats) before any use so
        // they are simultaneously outstanding; compiler keeps them as
        // global_load_dwordx4 with one trailing s_waitcnt.
        const float4 t0 = g4[0];
        const float4 t1 = g4[1];
        const float4 t2 = g4[2];
        const float4 t3 = g4[3];
        const float4 t4 = g4[4];
        const float4 t5 = g4[5];
        const float4 t6 = g4[6];
        const float dx = dir[3 * i + 0];
        const float dy = dir[3 * i + 1];
        const float dz = dir[3 * i + 2];

        // SH deg-2 basis (shared across the 3 color channels)
        const float b0 = 0.282095f;
        const float b1 = -0.488603f * dy;
        const float b2 =  0.488603f * dz;
        const float b3 = -0.488603f * dx;
        const float b4 =  1.092548f * dx * dy;
        const float b5 = -1.092548f * dy * dz;
        const float b6 =  0.315392f * (2.0f * dz * dz - dx * dx - dy * dy);
        const float b7 = -1.092548f * dx * dz;
        const float b8 =  0.546274f * (dx * dx - dy * dy);

        c0 = b0 * t0.y + b1 * t0.z + b2 * t0.w + b3 * t1.x + b4 * t1.y
           + b5 * t1.z + b6 * t1.w + b7 * t2.x + b8 * t2.y;
        c1 = b0 * t2.z + b1 * t2.w + b2 * t3.x + b3 * t3.y + b4 * t3.z
           + b5 * t3.w + b6 * t4.x + b7 * t4.y + b8 * t4.z;
        c2 = b0 * t4.w + b1 * t5.x + b2 * t5.y + b3 * t5.z + b4 * t5.w
           + b5 * t6.x + b6 * t6.y + b7 * t6.z + b8 * t6.w;

        sg = fmaxf(t0.x, 0.0f);
    }

    // Output lines are fully overwritten every call — nontemporal stores skip
    // any read-allocate and avoid polluting L2/L3 (grid wants those caches).
    __builtin_nontemporal_store(c0, &out[3 * i + 0]);
    __builtin_nontemporal_store(c1, &out[3 * i + 1]);
    __builtin_nontemporal_store(c2, &out[3 * i + 2]);
    __builtin_nontemporal_store(sg, &out[(size_t)3 * M + i]);
}

extern "C" void kernel_launch(void* const* d_in, const int* in_sizes, int n_in,
                              void* d_out, int out_size, void* d_ws, size_t ws_size,
                              hipStream_t stream) {
    const float* x    = (const float*)d_in[0];
    const float* dir  = (const float*)d_in[1];
    const float* grid = (const float*)d_in[2];
    float* out = (float*)d_out;

    const int M = in_sizes[0] / 3;   // 4194304
    const int block = 256;
    const int grid_dim = (M + block - 1) / block;
    nerf_fwd<<<grid_dim, block, 0, stream>>>(x, dir, grid, out, M);
}